// Round 6
// baseline (291.600 us; speedup 1.0000x reference)
//
#include <hip/hip_runtime.h>
#include <hip/hip_bf16.h>
#include <stdint.h>

#define TT 2048
#define CC 1024
#define HH 16
#define DD 64

typedef __bf16 bf16;
typedef bf16 bf16x8 __attribute__((ext_vector_type(8)));
typedef float f32x4 __attribute__((ext_vector_type(4)));
typedef float f32x16 __attribute__((ext_vector_type(16)));
typedef unsigned u32x4 __attribute__((ext_vector_type(4)));
typedef unsigned u32x2 __attribute__((ext_vector_type(2)));

#define MFMA16(a, b, c) __builtin_amdgcn_mfma_f32_16x16x32_bf16(a, b, c, 0, 0, 0)
#define MFMA32(a, b, c) __builtin_amdgcn_mfma_f32_32x32x16_bf16(a, b, c, 0, 0, 0)

// 1/8 (attn scale) * 1/ln2 (exp2 domain), folded into Q at QKV-GEMM epilogue
#define SCLQ 0.18033688011112043f

typedef __attribute__((address_space(1))) unsigned int u32_g;
typedef __attribute__((address_space(3))) unsigned int u32_l;

__device__ __forceinline__ void gload_lds16(const void* g, void* l) {
  __builtin_amdgcn_global_load_lds((u32_g*)g, (u32_l*)l, 16, 0, 0);
}

__device__ __forceinline__ unsigned cvtpk(float a, float b) {
  unsigned r;
  asm("v_cvt_pk_bf16_f32 %0, %1, %2" : "=v"(r) : "v"(a), "v"(b));
  return r;
}

// HW cross-half swap: new_a = {a.lo32lanes, b.lo32lanes}, new_b = {a.hi, b.hi}
__device__ __forceinline__ void plswap(unsigned& a, unsigned& b) {
  asm("v_permlane32_swap_b32 %0, %1" : "+v"(a), "+v"(b));
}

// ---------------- convert x (f32 -> bf16), 8 elems/thread ----------------
__global__ __launch_bounds__(256) void k_cvt(const float* __restrict__ in,
                                             bf16* __restrict__ out, int n8) {
  int i = blockIdx.x * 256 + threadIdx.x;
  if (i >= n8) return;
  const float4* p = (const float4*)in + (size_t)i * 2;
  float4 a = p[0], b = p[1];
  bf16x8 o;
  o[0] = (bf16)a.x; o[1] = (bf16)a.y; o[2] = (bf16)a.z; o[3] = (bf16)a.w;
  o[4] = (bf16)b.x; o[5] = (bf16)b.y; o[6] = (bf16)b.z; o[7] = (bf16)b.w;
  *((bf16x8*)out + i) = o;
}

// ------------- transpose weight: in f32 [R][C] -> out bf16 [C][R] -------------
__global__ __launch_bounds__(256) void k_transpose_w(const float* __restrict__ in,
                                                     bf16* __restrict__ out,
                                                     int R, int C) {
  __shared__ float tile[64][65];
  int tcn = C >> 6;
  int tc = blockIdx.x % tcn;
  int tr = blockIdx.x / tcn;
  int t = threadIdx.x;
  int r0 = t >> 4;
  int cv = t & 15;
  const float4* src = (const float4*)(in + (size_t)(tr * 64) * C + tc * 64);
  int strideV = C >> 2;
#pragma unroll
  for (int p = 0; p < 4; ++p) {
    int r = r0 + p * 16;
    float4 v = src[(size_t)r * strideV + cv];
    tile[r][cv * 4 + 0] = v.x;
    tile[r][cv * 4 + 1] = v.y;
    tile[r][cv * 4 + 2] = v.z;
    tile[r][cv * 4 + 3] = v.w;
  }
  __syncthreads();
  int nn0 = t >> 3;
  int ck = t & 7;
#pragma unroll
  for (int p = 0; p < 2; ++p) {
    int nn = nn0 + p * 32;
    bf16x8 o;
#pragma unroll
    for (int i = 0; i < 8; ++i) o[i] = (bf16)tile[ck * 8 + i][nn];
    *(bf16x8*)(out + (size_t)(tc * 64 + nn) * R + tr * 64 + ck * 8) = o;
  }
}

// ---- GEMM 256x256 tile, BK=32, ring-3 LDS, counted vmcnt, XCD supertiles ----
// C[m][n] = A[m][k] * Bt[n][k] + bias[n].  K = 1024 (32 K-steps).
// 512 threads = 8 waves (2M x 4N), per-wave 128x64 output.
// Block mapping: xcd = bid&7 owns tm-band [xcd*4, xcd*4+4); groups of 2 tm x
// all tn, tn-major -> per-XCD working set ~2MB A + streamed B fits 4MB L2.
// MODE 0: scatter Q (pre-scaled SCLQ) [BH][T][D], K [BH][T][D], Vt [BH][D][T].
// MODE 1: f32 out [M][N].
template <int MODE>
__global__ __launch_bounds__(512) void k_gemm(const bf16* __restrict__ A,
                                              const bf16* __restrict__ Bt,
                                              int Kdim, int N,
                                              const float* __restrict__ bias,
                                              bf16* __restrict__ Qd,
                                              bf16* __restrict__ Kd,
                                              bf16* __restrict__ Vd,
                                              float* __restrict__ Fd) {
  __shared__ __align__(16) char lds[98304];  // 3 slots x (A 16KB + B 16KB)
  int gx = N >> 8;  // 12 (MODE 0) or 4 (MODE 1)
  int bid = blockIdx.x;
  int xcd = bid & 7;
  int idx = bid >> 3;
  int half = idx / (2 * gx);
  int t2 = idx % (2 * gx);
  int tn = t2 >> 1;
  int tm = xcd * 4 + half * 2 + (t2 & 1);

  int tid = threadIdx.x;
  int wid = tid >> 6, lane = tid & 63;
  int wm = (wid >> 2) * 128;  // 0 / 128
  int wn = (wid & 3) * 64;    // 0..192

  f32x4 acc[8][4];
#pragma unroll
  for (int i = 0; i < 8; ++i)
#pragma unroll
    for (int j = 0; j < 4; ++j) acc[i][j] = {0.f, 0.f, 0.f, 0.f};

  // staging geometry: round c: row = c*128 + tid/4; 16B slot = tid&3.
  // read swizzle f(row) = (row>>1)&3 -> pre-swizzle source by same XOR.
  int srow[2], ssrc[2], sdst[2];
#pragma unroll
  for (int c = 0; c < 2; ++c) {
    srow[c] = c * 128 + (tid >> 2);
    ssrc[c] = (((tid & 3) ^ ((srow[c] >> 1) & 3)) << 3);  // bf16 elems
    sdst[c] = c * 8192 + tid * 16;
  }
  const bf16* Abase = A + (size_t)(tm * 256) * Kdim;
  const bf16* Bbase = Bt + (size_t)(tn * 256) * Kdim;

  int NT = Kdim >> 5;  // 32

  // prologue: stage tiles 0,1 into slots 0,1
#pragma unroll
  for (int t0 = 0; t0 < 2; ++t0) {
    char* sa = lds + t0 * 32768;
    char* sb = sa + 16384;
    int ks = t0 * 32;
#pragma unroll
    for (int c = 0; c < 2; ++c) {
      gload_lds16(Abase + (size_t)srow[c] * Kdim + ks + ssrc[c], sa + sdst[c]);
      gload_lds16(Bbase + (size_t)srow[c] * Kdim + ks + ssrc[c], sb + sdst[c]);
    }
  }

  // hoisted fragment read byte-offsets (per-thread constants)
  int fr = lane & 15;
  int abyte[8], bbyte[4];
#pragma unroll
  for (int i = 0; i < 8; ++i) {
    int ra = wm + i * 16 + fr;
    abyte[i] = ra * 64 + ((((lane >> 4) ^ ((ra >> 1) & 3))) << 4);
  }
#pragma unroll
  for (int j = 0; j < 4; ++j) {
    int rb = wn + j * 16 + fr;
    bbyte[j] = rb * 64 + ((((lane >> 4) ^ ((rb >> 1) & 3))) << 4);
  }

  int cs = 0, ps = 2;
#pragma unroll 1
  for (int t = 0; t < NT; ++t) {
    if (t < NT - 1)
      asm volatile("s_waitcnt vmcnt(4)" ::: "memory");
    else
      asm volatile("s_waitcnt vmcnt(0)" ::: "memory");
    __builtin_amdgcn_s_barrier();
    __builtin_amdgcn_sched_barrier(0);

    if (t + 2 < NT) {
      char* sa = lds + ps * 32768;
      char* sb = sa + 16384;
      int ks = (t + 2) * 32;
#pragma unroll
      for (int c = 0; c < 2; ++c) {
        gload_lds16(Abase + (size_t)srow[c] * Kdim + ks + ssrc[c], sa + sdst[c]);
        gload_lds16(Bbase + (size_t)srow[c] * Kdim + ks + ssrc[c], sb + sdst[c]);
      }
    }

    const char* sa = lds + cs * 32768;
    const char* sb = sa + 16384;
    bf16x8 af[8], bfv[4];
#pragma unroll
    for (int j = 0; j < 4; ++j) bfv[j] = *(const bf16x8*)(sb + bbyte[j]);
#pragma unroll
    for (int i = 0; i < 8; ++i) af[i] = *(const bf16x8*)(sa + abyte[i]);
    __builtin_amdgcn_s_setprio(1);
#pragma unroll
    for (int i = 0; i < 8; ++i)
#pragma unroll
      for (int j = 0; j < 4; ++j) acc[i][j] = MFMA16(af[i], bfv[j], acc[i][j]);
    __builtin_amdgcn_s_setprio(0);

    cs = (cs == 2) ? 0 : cs + 1;
    ps = (ps == 2) ? 0 : ps + 1;
  }

  int r0 = (lane >> 4) * 4;
  int cn = lane & 15;
  if (MODE == 0) {
    int n0 = tn * 256 + wn;
    int which = n0 >> 10;  // uniform per wave
#pragma unroll
    for (int j = 0; j < 4; ++j) {
      int n = n0 + j * 16 + cn;
      float bv = bias[n];
      int h = (n >> 6) & 15;
      int d = n & 63;
#pragma unroll
      for (int i = 0; i < 8; ++i) {
#pragma unroll
        for (int r = 0; r < 4; ++r) {
          int m = tm * 256 + wm + i * 16 + r0 + r;
          int b = m >> 11, t = m & 2047;
          float val = acc[i][j][r] + bv;
          if (which == 0)
            Qd[(((size_t)(b * HH + h)) * TT + t) * DD + d] = (bf16)(val * SCLQ);
          else if (which == 1)
            Kd[(((size_t)(b * HH + h)) * TT + t) * DD + d] = (bf16)val;
          else  // V transposed: [BH][D][T]
            Vd[(((size_t)(b * HH + h)) * DD + d) * TT + t] = (bf16)val;
        }
      }
    }
  } else {
#pragma unroll
    for (int j = 0; j < 4; ++j) {
      int n = tn * 256 + wn + j * 16 + cn;
      float bv = bias[n];
#pragma unroll
      for (int i = 0; i < 8; ++i) {
#pragma unroll
        for (int r = 0; r < 4; ++r) {
          int m = tm * 256 + wm + i * 16 + r0 + r;
          Fd[(size_t)m * N + n] = acc[i][j][r] + bv;
        }
      }
    }
  }
}

// ---------------- Flash attention (causal), 32x32 MFMA, swapped-QK^T ----------------
// Max-free softmax: scores bounded (|qk|/8/ln2 << 127), P = exp2(s) directly.
// Q pre-scaled by SCLQ. Lane owns q-col = lane&31; kv rows (g&3)+8*(g>>2)+4*hi.
template <bool MASKED>
__device__ __forceinline__ void attn_tile(const char* __restrict__ sK,
                                          const char* __restrict__ sV,
                                          const bf16x8 qf[4],
                                          f32x16& o0, f32x16& o1, float& lrun,
                                          int base0, const int* __restrict__ colp,
                                          int hi, int qabs, int kvb) {
  f32x16 s0, s1;
#pragma unroll
  for (int g = 0; g < 16; ++g) { s0[g] = 0.f; s1[g] = 0.f; }
#pragma unroll
  for (int c = 0; c < 4; ++c) {
    bf16x8 kf0 = *(const bf16x8*)(sK + base0 + colp[c]);
    bf16x8 kf1 = *(const bf16x8*)(sK + base0 + 4096 + colp[c]);
    s0 = MFMA32(kf0, qf[c], s0);
    s1 = MFMA32(kf1, qf[c], s1);
  }
  float rs = 0.f;
#pragma unroll
  for (int g = 0; g < 16; ++g) {
    float p0 = __builtin_amdgcn_exp2f(s0[g]);
    float p1 = __builtin_amdgcn_exp2f(s1[g]);
    if (MASKED) {
      int kvr = (g & 3) + 8 * (g >> 2) + 4 * hi;
      p0 = (kvb + kvr <= qabs) ? p0 : 0.f;
      p1 = (kvb + 32 + kvr <= qabs) ? p1 : 0.f;
    }
    s0[g] = p0; s1[g] = p1;
    rs += p0 + p1;
  }
  lrun += rs;

  unsigned pk[8], qk[8];
#pragma unroll
  for (int i = 0; i < 8; ++i) {
    pk[i] = cvtpk(s0[2 * i], s0[2 * i + 1]);
    qk[i] = cvtpk(s1[2 * i], s1[2 * i + 1]);
  }
  plswap(pk[0], pk[2]); plswap(pk[1], pk[3]);
  plswap(pk[4], pk[6]); plswap(pk[5], pk[7]);
  plswap(qk[0], qk[2]); plswap(qk[1], qk[3]);
  plswap(qk[4], qk[6]); plswap(qk[5], qk[7]);

  bf16x8 pfr[4];
  pfr[0] = __builtin_bit_cast(bf16x8, (u32x4){pk[0], pk[1], pk[2], pk[3]});
  pfr[1] = __builtin_bit_cast(bf16x8, (u32x4){pk[4], pk[5], pk[6], pk[7]});
  pfr[2] = __builtin_bit_cast(bf16x8, (u32x4){qk[0], qk[1], qk[2], qk[3]});
  pfr[3] = __builtin_bit_cast(bf16x8, (u32x4){qk[4], qk[5], qk[6], qk[7]});

  // O^T += V^T * P^T
#pragma unroll
  for (int cc = 0; cc < 4; ++cc) {
    bf16x8 vf0 = *(const bf16x8*)(sV + base0 + colp[cc]);
    bf16x8 vf1 = *(const bf16x8*)(sV + base0 + 4096 + colp[cc]);
    o0 = MFMA32(vf0, pfr[cc], o0);
    o1 = MFMA32(vf1, pfr[cc], o1);
  }
}

// Block = 4 waves x 32 q-rows, TWO q-tiles per block (qt=pair and 15-pair)
// -> uniform 34 KV-tiles/block, 512 blocks (2/CU), no causal tail imbalance.
__global__ __launch_bounds__(256) void k_attn(const bf16* __restrict__ Qg,
                                              const bf16* __restrict__ Kg,
                                              const bf16* __restrict__ Vtg,
                                              bf16* __restrict__ O) {
  __shared__ __align__(16) char lds[32768];  // 2 bufs x (8KB K + 8KB Vt)

  int bid = blockIdx.x;
  int bh = (bid & 7) * 8 + ((bid >> 3) & 7);  // heads grouped per XCD
  int pair = bid >> 6;                        // 0..7
  int wid = threadIdx.x >> 6, lane = threadIdx.x & 63;
  int l31 = lane & 31, hi = lane >> 5;

  const bf16* Qh = Qg + (size_t)bh * TT * DD;
  const bf16* Kh = Kg + (size_t)bh * TT * DD;
  const bf16* Vh = Vtg + (size_t)bh * DD * TT;

  // hoisted LDS read addressing
  int base0 = l31 * 128;
  int colp[4];
#pragma unroll
  for (int c = 0; c < 4; ++c) colp[c] = (32 * c + 16 * hi) ^ ((l31 & 7) << 4);

  // staging geometry (pre-swizzled source, linear LDS dest)
  int soff[2], srow[2], scol[2];
#pragma unroll
  for (int c = 0; c < 2; ++c) {
    int off = (wid * 2 + c) * 1024 + lane * 16;
    soff[c] = (wid * 2 + c) * 1024;
    srow[c] = off >> 7;
    scol[c] = (off & 127) ^ ((srow[c] & 7) << 4);
  }

  int b = bh >> 4, h = bh & 15;

#pragma unroll 1
  for (int half = 0; half < 2; ++half) {
    int qt = half ? (15 - pair) : pair;
    int qb = qt * 128;
    int qw = qb + wid * 32;
    int qabs = qw + l31;

    bf16x8 qf[4];
#pragma unroll
    for (int c = 0; c < 4; ++c)
      qf[c] = *(const bf16x8*)(Qh + (size_t)qabs * DD + c * 16 + hi * 8);

    f32x16 o0, o1;
#pragma unroll
    for (int g = 0; g < 16; ++g) { o0[g] = 0.f; o1[g] = 0.f; }
    float lrun = 0.f;

    int ntile = 2 * qt + 2;

    // prologue: stage tile 0 into buf 0
#pragma unroll
    for (int c = 0; c < 2; ++c) {
      gload_lds16(Kh + (size_t)srow[c] * DD + (scol[c] >> 1), lds + soff[c]);
      gload_lds16(Vh + (size_t)srow[c] * TT + (scol[c] >> 1), lds + 8192 + soff[c]);
    }
    __syncthreads();

    int cur = 0;
    for (int tk = 0; tk < ntile; ++tk) {
      int kvb = tk * 64;
      if (tk + 1 < ntile) {
        int kvn = kvb + 64;
        char* dK = lds + (cur ^ 1) * 16384;
        char* dV = dK + 8192;
#pragma unroll
        for (int c = 0; c < 2; ++c) {
          gload_lds16(Kh + (size_t)(kvn + srow[c]) * DD + (scol[c] >> 1), dK + soff[c]);
          gload_lds16(Vh + (size_t)srow[c] * TT + kvn + (scol[c] >> 1), dV + soff[c]);
        }
      }
      const char* sK = lds + cur * 16384;
      const char* sV = sK + 8192;
      if (kvb + 63 <= qw)
        attn_tile<false>(sK, sV, qf, o0, o1, lrun, base0, colp, hi, qabs, kvb);
      else if (kvb <= qw + 31)
        attn_tile<true>(sK, sV, qf, o0, o1, lrun, base0, colp, hi, qabs, kvb);
      __syncthreads();
      cur ^= 1;
    }

    // epilogue: combine row-sum halves once; lane owns q-col
    lrun += __shfl_xor(lrun, 32);
    float rl = 1.0f / lrun;
    bf16* baseO = O + ((size_t)(b * TT + qabs)) * CC + h * 64;
#pragma unroll
    for (int G = 0; G < 4; ++G) {
      unsigned w0 = cvtpk(o0[4 * G] * rl, o0[4 * G + 1] * rl);
      unsigned w1 = cvtpk(o0[4 * G + 2] * rl, o0[4 * G + 3] * rl);
      *(u32x2*)(baseO + 8 * G + 4 * hi) = (u32x2){w0, w1};
      unsigned w2 = cvtpk(o1[4 * G] * rl, o1[4 * G + 1] * rl);
      unsigned w3 = cvtpk(o1[4 * G + 2] * rl, o1[4 * G + 3] * rl);
      *(u32x2*)(baseO + 32 + 8 * G + 4 * hi) = (u32x2){w2, w3};
    }
  }
}

// ---------------- launch ----------------
extern "C" void kernel_launch(void* const* d_in, const int* in_sizes, int n_in,
                              void* d_out, int out_size, void* d_ws, size_t ws_size,
                              hipStream_t stream) {
  const float* x = (const float*)d_in[0];
  // d_in[1] = attn_mask (causal tril) — hardcoded, unused
  const float* Wqkv = (const float*)d_in[2];
  const float* bqkv = (const float*)d_in[3];
  const float* Wout = (const float*)d_in[4];
  const float* bout = (const float*)d_in[5];
  float* out = (float*)d_out;

  char* ws = (char*)d_ws;
  bf16* xb  = (bf16*)(ws);                      // 16 MB  [8192][1024]
  bf16* wt1 = (bf16*)(ws + (16u << 20));        //  6 MB  [3072][1024]
  bf16* wt2 = (bf16*)(ws + (22u << 20));        //  2 MB  [1024][1024]
  bf16* Qb  = (bf16*)(ws + (24u << 20));        // 16 MB  [64][2048][64] (pre-scaled)
  bf16* Kb  = (bf16*)(ws + (40u << 20));        // 16 MB
  bf16* Vt  = (bf16*)(ws + (56u << 20));        // 16 MB  [64][64][2048] (transposed)
  bf16* Ob  = (bf16*)(ws + (72u << 20));        // 16 MB  [8192][1024]

  k_cvt<<<4096, 256, 0, stream>>>(x, xb, (4 * TT * CC) / 8);
  k_transpose_w<<<768, 256, 0, stream>>>(Wqkv, wt1, 1024, 3072);
  k_transpose_w<<<256, 256, 0, stream>>>(Wout, wt2, 1024, 1024);
  k_gemm<0><<<384, 512, 0, stream>>>(xb, wt1, 1024, 3072, bqkv, Qb, Kb, Vt, nullptr);
  k_attn<<<512, 256, 0, stream>>>(Qb, Kb, Vt, Ob);
  k_gemm<1><<<128, 512, 0, stream>>>(Ob, wt2, 1024, 1024, bout, nullptr, nullptr, nullptr, out);
}

// Round 8
// 286.725 us; speedup vs baseline: 1.0170x; 1.0170x over previous
//
#include <hip/hip_runtime.h>
#include <hip/hip_bf16.h>
#include <stdint.h>

#define TT 2048
#define CC 1024
#define HH 16
#define DD 64

typedef __bf16 bf16;
typedef bf16 bf16x8 __attribute__((ext_vector_type(8)));
typedef float f32x4 __attribute__((ext_vector_type(4)));
typedef float f32x16 __attribute__((ext_vector_type(16)));
typedef unsigned u32x4 __attribute__((ext_vector_type(4)));
typedef unsigned u32x2 __attribute__((ext_vector_type(2)));

#define MFMA16(a, b, c) __builtin_amdgcn_mfma_f32_16x16x32_bf16(a, b, c, 0, 0, 0)
#define MFMA32(a, b, c) __builtin_amdgcn_mfma_f32_32x32x16_bf16(a, b, c, 0, 0, 0)

// 1/8 (attn scale) * 1/ln2 (exp2 domain), folded into Q at QKV-GEMM epilogue
#define SCLQ 0.18033688011112043f

typedef __attribute__((address_space(1))) unsigned int u32_g;
typedef __attribute__((address_space(3))) unsigned int u32_l;

__device__ __forceinline__ void gload_lds16(const void* g, void* l) {
  __builtin_amdgcn_global_load_lds((u32_g*)g, (u32_l*)l, 16, 0, 0);
}

__device__ __forceinline__ unsigned cvtpk(float a, float b) {
  unsigned r;
  asm("v_cvt_pk_bf16_f32 %0, %1, %2" : "=v"(r) : "v"(a), "v"(b));
  return r;
}

// HW cross-half swap: new_a = {a.lo32lanes, b.lo32lanes}, new_b = {a.hi, b.hi}
__device__ __forceinline__ void plswap(unsigned& a, unsigned& b) {
  asm("v_permlane32_swap_b32 %0, %1" : "+v"(a), "+v"(b));
}

// ---------------- convert x (f32 -> bf16), 8 elems/thread ----------------
__global__ __launch_bounds__(256) void k_cvt(const float* __restrict__ in,
                                             bf16* __restrict__ out, int n8) {
  int i = blockIdx.x * 256 + threadIdx.x;
  if (i >= n8) return;
  const float4* p = (const float4*)in + (size_t)i * 2;
  float4 a = p[0], b = p[1];
  bf16x8 o;
  o[0] = (bf16)a.x; o[1] = (bf16)a.y; o[2] = (bf16)a.z; o[3] = (bf16)a.w;
  o[4] = (bf16)b.x; o[5] = (bf16)b.y; o[6] = (bf16)b.z; o[7] = (bf16)b.w;
  *((bf16x8*)out + i) = o;
}

// ------------- transpose weight: in f32 [R][C] -> out bf16 [C][R] -------------
__global__ __launch_bounds__(256) void k_transpose_w(const float* __restrict__ in,
                                                     bf16* __restrict__ out,
                                                     int R, int C) {
  __shared__ float tile[64][65];
  int tcn = C >> 6;
  int tc = blockIdx.x % tcn;
  int tr = blockIdx.x / tcn;
  int t = threadIdx.x;
  int r0 = t >> 4;
  int cv = t & 15;
  const float4* src = (const float4*)(in + (size_t)(tr * 64) * C + tc * 64);
  int strideV = C >> 2;
#pragma unroll
  for (int p = 0; p < 4; ++p) {
    int r = r0 + p * 16;
    float4 v = src[(size_t)r * strideV + cv];
    tile[r][cv * 4 + 0] = v.x;
    tile[r][cv * 4 + 1] = v.y;
    tile[r][cv * 4 + 2] = v.z;
    tile[r][cv * 4 + 3] = v.w;
  }
  __syncthreads();
  int nn0 = t >> 3;
  int ck = t & 7;
#pragma unroll
  for (int p = 0; p < 2; ++p) {
    int nn = nn0 + p * 32;
    bf16x8 o;
#pragma unroll
    for (int i = 0; i < 8; ++i) o[i] = (bf16)tile[ck * 8 + i][nn];
    *(bf16x8*)(out + (size_t)(tc * 64 + nn) * R + tr * 64 + ck * 8) = o;
  }
}

// ---------------- 8-phase GEMM (m201-style), BK=64, counted vmcnt ----------------
// C[m][n] = A[m][k] * Bt[n][k] + bias[n].  K = 1024 (16 K-tiles).
// MODE 0: BM=256 (MREP=8), BN=256; scatter Q(SCLQ)/K [BH][T][D], Vt [BH][D][T].
// MODE 1: BM=128 (MREP=4), BN=256; f32 out [M][N].
// 512 threads = 8 waves (2M x 4N); per-wave BM/2 x 64 output.
// LDS: 2 bufs x (A BM*128B + B 256*128B). Stage unit = 8KB (64 rows), 1 load/thr.
// Per K-tile: 4 phases (g,s): reads { B[s] (g==0), A-frags group g slice s },
// one stage set, barrier, lgkmcnt(0)+sched_barrier, setprio(1)+MFMA, barrier.
// Stage schedule (verified vs last-read phase): P0: A-hi units of t+1 (other buf);
// P2: A-lo units + first B units of t+2 (current buf, regions already consumed);
// P3: remaining B units of t+2; vmcnt(6|4) once per tile at P3 end (0 for last).
template <int MODE>
__global__ __launch_bounds__(512, 1) void k_gemm8(const bf16* __restrict__ A,
                                                  const bf16* __restrict__ Bt,
                                                  int Kd, int N,
                                                  const float* __restrict__ bias,
                                                  bf16* __restrict__ Qd,
                                                  bf16* __restrict__ Kdst,
                                                  bf16* __restrict__ Vd,
                                                  float* __restrict__ Fd) {
  constexpr int MREP = (MODE == 0) ? 8 : 4;
  constexpr int BM = MREP * 32;          // 256 / 128
  constexpr int ABYTES = BM * 128;       // 32KB / 16KB
  constexpr int BUF = ABYTES + 256 * 128;  // 64KB / 48KB
  __shared__ __align__(16) char lds[2 * BUF];

  int nwg = gridDim.x;
  int q8 = nwg >> 3;
  int swz = (blockIdx.x & 7) * q8 + (blockIdx.x >> 3);  // nwg % 8 == 0
  int gx = N >> 8;
  int tm = swz / gx, tn = swz % gx;
  int tid = threadIdx.x, wid = tid >> 6, lane = tid & 63;
  int wmr = (wid >> 2) * (BM / 2);
  int wnr = (wid & 3) * 64;

  f32x4 acc[MREP][4];
#pragma unroll
  for (int i = 0; i < MREP; ++i)
#pragma unroll
    for (int j = 0; j < 4; ++j) acc[i][j] = {0.f, 0.f, 0.f, 0.f};

  // --- staging constants: unit = 8KB = 64 rows x 128B; linear dest, swz source
  int urow = tid >> 3;                          // 0..63
  int ubyte = tid * 16;
  int scole = (((tid & 7) ^ (urow & 7)) << 4) >> 1;  // bf16 elems
  const bf16* Asrc = A + (size_t)(tm * BM + urow) * Kd + scole;
  const bf16* Bsrc = Bt + (size_t)(tn * 256 + urow) * Kd + scole;

#define STA(tt, qq, bb)                                               \
  gload_lds16(Asrc + (size_t)((qq) * 64) * Kd + (tt) * 64,            \
              lds + (bb) * BUF + (qq) * 8192 + ubyte)
#define STB(tt, qq, bb)                                               \
  gload_lds16(Bsrc + (size_t)((qq) * 64) * Kd + (tt) * 64,            \
              lds + (bb) * BUF + ABYTES + (qq) * 8192 + ubyte)

  // --- fragment read constants
  int abase[MREP], bbase[4], col2[2];
#pragma unroll
  for (int i = 0; i < MREP; ++i) abase[i] = (wmr + i * 16 + (lane & 15)) * 128;
#pragma unroll
  for (int j = 0; j < 4; ++j) bbase[j] = ABYTES + (wnr + j * 16 + (lane & 15)) * 128;
#pragma unroll
  for (int s = 0; s < 2; ++s)
    col2[s] = (s * 64 + ((lane >> 4) << 4)) ^ ((lane & 7) << 4);

  int NT = Kd >> 6;  // 16

  // --- prologue: tile0 fully + tile1 minus its A-hi units
  if constexpr (MODE == 0) {
#pragma unroll
    for (int q = 0; q < 4; ++q) { STA(0, q, 0); STB(0, q, 0); }
    STA(1, 0, 1); STA(1, 2, 1); STB(1, 0, 1);
    STB(1, 1, 1); STB(1, 2, 1); STB(1, 3, 1);
    asm volatile("s_waitcnt vmcnt(6)" ::: "memory");
  } else {
    STA(0, 0, 0); STA(0, 1, 0);
#pragma unroll
    for (int q = 0; q < 4; ++q) STB(0, q, 0);
#pragma unroll
    for (int q = 0; q < 4; ++q) STB(1, q, 1);
    asm volatile("s_waitcnt vmcnt(4)" ::: "memory");
  }
  __builtin_amdgcn_s_barrier();

  bf16x8 breg[2][4];

#define PHASE(g, s, STAGES, TAIL)                                              \
  do {                                                                         \
    bf16x8 afr[MREP / 2];                                                      \
    if ((g) == 0) {                                                            \
      _Pragma("unroll") for (int j = 0; j < 4; ++j)                            \
          breg[s][j] = *(const bf16x8*)(cbuf + bbase[j] + col2[s]);            \
    }                                                                          \
    _Pragma("unroll") for (int i = 0; i < MREP / 2; ++i)                       \
        afr[i] = *(const bf16x8*)(cbuf + abase[(g) * (MREP / 2) + i] + col2[s]); \
    STAGES;                                                                    \
    __builtin_amdgcn_s_barrier();                                              \
    asm volatile("s_waitcnt lgkmcnt(0)" ::: "memory");                         \
    __builtin_amdgcn_sched_barrier(0);                                         \
    __builtin_amdgcn_s_setprio(1);                                             \
    _Pragma("unroll") for (int i = 0; i < MREP / 2; ++i)                       \
        _Pragma("unroll") for (int j = 0; j < 4; ++j)                          \
            acc[(g) * (MREP / 2) + i][j] =                                     \
                MFMA16(afr[i], breg[s][j], acc[(g) * (MREP / 2) + i][j]);      \
    __builtin_amdgcn_s_setprio(0);                                             \
    __builtin_amdgcn_sched_barrier(0);                                         \
    TAIL;                                                                      \
    __builtin_amdgcn_s_barrier();                                              \
  } while (0)

#pragma unroll 1
  for (int t = 0; t < NT; ++t) {
    int cur = t & 1;
    const char* cbuf = lds + cur * BUF;

    PHASE(0, 0,
          {
            if (t + 1 < NT) {
              if constexpr (MODE == 0) { STA(t + 1, 1, cur ^ 1); STA(t + 1, 3, cur ^ 1); }
              else { STA(t + 1, 0, cur ^ 1); STA(t + 1, 1, cur ^ 1); }
            }
          },
          {});
    PHASE(0, 1, {}, {});
    PHASE(1, 0,
          {
            if (t + 2 < NT) {
              if constexpr (MODE == 0) { STA(t + 2, 0, cur); STA(t + 2, 2, cur); STB(t + 2, 0, cur); }
              else { STB(t + 2, 0, cur); STB(t + 2, 1, cur); }
            }
          },
          {});
    PHASE(1, 1,
          {
            if (t + 2 < NT) {
              if constexpr (MODE == 0) { STB(t + 2, 1, cur); STB(t + 2, 2, cur); STB(t + 2, 3, cur); }
              else { STB(t + 2, 2, cur); STB(t + 2, 3, cur); }
            }
          },
          {
            if (t + 1 < NT) {
              if (t + 1 == NT - 1)
                asm volatile("s_waitcnt vmcnt(0)" ::: "memory");
              else if constexpr (MODE == 0)
                asm volatile("s_waitcnt vmcnt(6)" ::: "memory");
              else
                asm volatile("s_waitcnt vmcnt(4)" ::: "memory");
            }
          });
  }
#undef PHASE
#undef STA
#undef STB

  // --- epilogue
  int r0 = (lane >> 4) * 4;
  int cn = lane & 15;
  if constexpr (MODE == 0) {
    int n0 = tn * 256 + wnr;
    int which = n0 >> 10;  // wave-uniform
#pragma unroll
    for (int j = 0; j < 4; ++j) {
      int n = n0 + j * 16 + cn;
      float bv = bias[n];
      int h = (n >> 6) & 15;
      int d = n & 63;
#pragma unroll
      for (int i = 0; i < MREP; ++i) {
#pragma unroll
        for (int r = 0; r < 4; ++r) {
          int m = tm * BM + wmr + i * 16 + r0 + r;
          int b = m >> 11, tt = m & 2047;
          float val = acc[i][j][r] + bv;
          if (which == 0)
            Qd[(((size_t)(b * HH + h)) * TT + tt) * DD + d] = (bf16)(val * SCLQ);
          else if (which == 1)
            Kdst[(((size_t)(b * HH + h)) * TT + tt) * DD + d] = (bf16)val;
          else  // V transposed: [BH][D][T]
            Vd[(((size_t)(b * HH + h)) * DD + d) * TT + tt] = (bf16)val;
        }
      }
    }
  } else {
#pragma unroll
    for (int j = 0; j < 4; ++j) {
      int n = tn * 256 + wnr + j * 16 + cn;
      float bv = bias[n];
#pragma unroll
      for (int i = 0; i < MREP; ++i) {
#pragma unroll
        for (int r = 0; r < 4; ++r) {
          int m = tm * BM + wmr + i * 16 + r0 + r;
          Fd[(size_t)m * N + n] = acc[i][j][r] + bv;
        }
      }
    }
  }
}

// ---------------- Flash attention (causal), 32x32 MFMA, swapped-QK^T ----------------
// Max-free softmax: scores bounded (|qk|/8/ln2 << 127), P = exp2(s) directly.
// Q pre-scaled by SCLQ. Lane owns q-col = lane&31; kv rows (g&3)+8*(g>>2)+4*hi.
template <bool MASKED>
__device__ __forceinline__ void attn_tile(const char* __restrict__ sK,
                                          const char* __restrict__ sV,
                                          const bf16x8 qf[4],
                                          f32x16& o0, f32x16& o1, float& lrun,
                                          int base0, const int* __restrict__ colp,
                                          int hi, int qabs, int kvb) {
  f32x16 s0, s1;
#pragma unroll
  for (int g = 0; g < 16; ++g) { s0[g] = 0.f; s1[g] = 0.f; }
#pragma unroll
  for (int c = 0; c < 4; ++c) {
    bf16x8 kf0 = *(const bf16x8*)(sK + base0 + colp[c]);
    bf16x8 kf1 = *(const bf16x8*)(sK + base0 + 4096 + colp[c]);
    s0 = MFMA32(kf0, qf[c], s0);
    s1 = MFMA32(kf1, qf[c], s1);
  }
  float rs = 0.f;
#pragma unroll
  for (int g = 0; g < 16; ++g) {
    float p0 = __builtin_amdgcn_exp2f(s0[g]);
    float p1 = __builtin_amdgcn_exp2f(s1[g]);
    if (MASKED) {
      int kvr = (g & 3) + 8 * (g >> 2) + 4 * hi;
      p0 = (kvb + kvr <= qabs) ? p0 : 0.f;
      p1 = (kvb + 32 + kvr <= qabs) ? p1 : 0.f;
    }
    s0[g] = p0; s1[g] = p1;
    rs += p0 + p1;
  }
  lrun += rs;

  unsigned pk[8], qk[8];
#pragma unroll
  for (int i = 0; i < 8; ++i) {
    pk[i] = cvtpk(s0[2 * i], s0[2 * i + 1]);
    qk[i] = cvtpk(s1[2 * i], s1[2 * i + 1]);
  }
  plswap(pk[0], pk[2]); plswap(pk[1], pk[3]);
  plswap(pk[4], pk[6]); plswap(pk[5], pk[7]);
  plswap(qk[0], qk[2]); plswap(qk[1], qk[3]);
  plswap(qk[4], qk[6]); plswap(qk[5], qk[7]);

  bf16x8 pfr[4];
  pfr[0] = __builtin_bit_cast(bf16x8, (u32x4){pk[0], pk[1], pk[2], pk[3]});
  pfr[1] = __builtin_bit_cast(bf16x8, (u32x4){pk[4], pk[5], pk[6], pk[7]});
  pfr[2] = __builtin_bit_cast(bf16x8, (u32x4){qk[0], qk[1], qk[2], qk[3]});
  pfr[3] = __builtin_bit_cast(bf16x8, (u32x4){qk[4], qk[5], qk[6], qk[7]});

  // O^T += V^T * P^T
#pragma unroll
  for (int cc = 0; cc < 4; ++cc) {
    bf16x8 vf0 = *(const bf16x8*)(sV + base0 + colp[cc]);
    bf16x8 vf1 = *(const bf16x8*)(sV + base0 + 4096 + colp[cc]);
    o0 = MFMA32(vf0, pfr[cc], o0);
    o1 = MFMA32(vf1, pfr[cc], o1);
  }
}

// Block = 4 waves x 32 q-rows, TWO q-tiles per block (qt=pair and 15-pair)
// -> uniform 34 KV-tiles/block, 512 blocks (2/CU), no causal tail imbalance.
__global__ __launch_bounds__(256) void k_attn(const bf16* __restrict__ Qg,
                                              const bf16* __restrict__ Kg,
                                              const bf16* __restrict__ Vtg,
                                              bf16* __restrict__ O) {
  __shared__ __align__(16) char lds[32768];  // 2 bufs x (8KB K + 8KB Vt)

  int bid = blockIdx.x;
  int bh = (bid & 7) * 8 + ((bid >> 3) & 7);  // heads grouped per XCD
  int pair = bid >> 6;                        // 0..7
  int wid = threadIdx.x >> 6, lane = threadIdx.x & 63;
  int l31 = lane & 31, hi = lane >> 5;

  const bf16* Qh = Qg + (size_t)bh * TT * DD;
  const bf16* Kh = Kg + (size_t)bh * TT * DD;
  const bf16* Vh = Vtg + (size_t)bh * DD * TT;

  // hoisted LDS read addressing
  int base0 = l31 * 128;
  int colp[4];
#pragma unroll
  for (int c = 0; c < 4; ++c) colp[c] = (32 * c + 16 * hi) ^ ((l31 & 7) << 4);

  // staging geometry (pre-swizzled source, linear LDS dest)
  int soff[2], srow[2], scol[2];
#pragma unroll
  for (int c = 0; c < 2; ++c) {
    int off = (wid * 2 + c) * 1024 + lane * 16;
    soff[c] = (wid * 2 + c) * 1024;
    srow[c] = off >> 7;
    scol[c] = (off & 127) ^ ((srow[c] & 7) << 4);
  }

  int b = bh >> 4, h = bh & 15;

#pragma unroll 1
  for (int half = 0; half < 2; ++half) {
    int qt = half ? (15 - pair) : pair;
    int qb = qt * 128;
    int qw = qb + wid * 32;
    int qabs = qw + l31;

    bf16x8 qf[4];
#pragma unroll
    for (int c = 0; c < 4; ++c)
      qf[c] = *(const bf16x8*)(Qh + (size_t)qabs * DD + c * 16 + hi * 8);

    f32x16 o0, o1;
#pragma unroll
    for (int g = 0; g < 16; ++g) { o0[g] = 0.f; o1[g] = 0.f; }
    float lrun = 0.f;

    int ntile = 2 * qt + 2;

    // prologue: stage tile 0 into buf 0
#pragma unroll
    for (int c = 0; c < 2; ++c) {
      gload_lds16(Kh + (size_t)srow[c] * DD + (scol[c] >> 1), lds + soff[c]);
      gload_lds16(Vh + (size_t)srow[c] * TT + (scol[c] >> 1), lds + 8192 + soff[c]);
    }
    __syncthreads();

    int cur = 0;
    for (int tk = 0; tk < ntile; ++tk) {
      int kvb = tk * 64;
      if (tk + 1 < ntile) {
        int kvn = kvb + 64;
        char* dK = lds + (cur ^ 1) * 16384;
        char* dV = dK + 8192;
#pragma unroll
        for (int c = 0; c < 2; ++c) {
          gload_lds16(Kh + (size_t)(kvn + srow[c]) * DD + (scol[c] >> 1), dK + soff[c]);
          gload_lds16(Vh + (size_t)srow[c] * TT + kvn + (scol[c] >> 1), dV + soff[c]);
        }
      }
      const char* sK = lds + cur * 16384;
      const char* sV = sK + 8192;
      if (kvb + 63 <= qw)
        attn_tile<false>(sK, sV, qf, o0, o1, lrun, base0, colp, hi, qabs, kvb);
      else if (kvb <= qw + 31)
        attn_tile<true>(sK, sV, qf, o0, o1, lrun, base0, colp, hi, qabs, kvb);
      __syncthreads();
      cur ^= 1;
    }

    // epilogue: combine row-sum halves once; lane owns q-col
    lrun += __shfl_xor(lrun, 32);
    float rl = 1.0f / lrun;
    bf16* baseO = O + ((size_t)(b * TT + qabs)) * CC + h * 64;
#pragma unroll
    for (int G = 0; G < 4; ++G) {
      unsigned w0 = cvtpk(o0[4 * G] * rl, o0[4 * G + 1] * rl);
      unsigned w1 = cvtpk(o0[4 * G + 2] * rl, o0[4 * G + 3] * rl);
      *(u32x2*)(baseO + 8 * G + 4 * hi) = (u32x2){w0, w1};
      unsigned w2 = cvtpk(o1[4 * G] * rl, o1[4 * G + 1] * rl);
      unsigned w3 = cvtpk(o1[4 * G + 2] * rl, o1[4 * G + 3] * rl);
      *(u32x2*)(baseO + 32 + 8 * G + 4 * hi) = (u32x2){w2, w3};
    }
  }
}

// ---------------- launch ----------------
extern "C" void kernel_launch(void* const* d_in, const int* in_sizes, int n_in,
                              void* d_out, int out_size, void* d_ws, size_t ws_size,
                              hipStream_t stream) {
  const float* x = (const float*)d_in[0];
  // d_in[1] = attn_mask (causal tril) — hardcoded, unused
  const float* Wqkv = (const float*)d_in[2];
  const float* bqkv = (const float*)d_in[3];
  const float* Wout = (const float*)d_in[4];
  const float* bout = (const float*)d_in[5];
  float* out = (float*)d_out;

  char* ws = (char*)d_ws;
  bf16* xb  = (bf16*)(ws);                      // 16 MB  [8192][1024]
  bf16* wt1 = (bf16*)(ws + (16u << 20));        //  6 MB  [3072][1024]
  bf16* wt2 = (bf16*)(ws + (22u << 20));        //  2 MB  [1024][1024]
  bf16* Qb  = (bf16*)(ws + (24u << 20));        // 16 MB  [64][2048][64] (pre-scaled)
  bf16* Kb  = (bf16*)(ws + (40u << 20));        // 16 MB
  bf16* Vt  = (bf16*)(ws + (56u << 20));        // 16 MB  [64][64][2048] (transposed)
  bf16* Ob  = (bf16*)(ws + (72u << 20));        // 16 MB  [8192][1024]

  k_cvt<<<4096, 256, 0, stream>>>(x, xb, (4 * TT * CC) / 8);
  k_transpose_w<<<768, 256, 0, stream>>>(Wqkv, wt1, 1024, 3072);
  k_transpose_w<<<256, 256, 0, stream>>>(Wout, wt2, 1024, 1024);
  k_gemm8<0><<<384, 512, 0, stream>>>(xb, wt1, 1024, 3072, bqkv, Qb, Kb, Vt, nullptr);
  k_attn<<<512, 256, 0, stream>>>(Qb, Kb, Vt, Ob);
  k_gemm8<1><<<256, 512, 0, stream>>>(Ob, wt2, 1024, 1024, bout, nullptr, nullptr, nullptr, out);
}